// Round 1
// baseline (126.037 us; speedup 1.0000x reference)
//
#include <hip/hip_runtime.h>
#include <hip/hip_bf16.h>

static constexpr float kEps = 1e-6f;

// Fused relu -> tp-sum -> RMSNorm.
// One block (256 threads) per token row. TP and ITERS (= hidden/(256*4))
// are compile-time so all 4*TP loads per iteration issue independently
// (max memory-level parallelism) and r[] stays in registers.
template <int TP, int ITERS>
__global__ __launch_bounds__(256) void relu_ar_rmsnorm_kernel(
    const float* __restrict__ x,      // [TP, tokens, hidden]
    const float* __restrict__ w,      // [hidden]
    float* __restrict__ out,          // [tokens, hidden]
    int tokens, int hidden)
{
    const int tid = threadIdx.x;
    const long long row = (long long)blockIdx.x * hidden;
    const long long rstride = (long long)tokens * hidden;

    float4 r[ITERS];
    float sumsq = 0.f;

#pragma unroll
    for (int i = 0; i < ITERS; ++i) {
        const int e = (i * 256 + tid) * 4;   // coalesced: consecutive lanes -> consecutive float4
        float4 s = make_float4(0.f, 0.f, 0.f, 0.f);
#pragma unroll
        for (int rk = 0; rk < TP; ++rk) {
            const float4 a = *reinterpret_cast<const float4*>(x + rk * rstride + row + e);
            s.x += fmaxf(a.x, 0.f);
            s.y += fmaxf(a.y, 0.f);
            s.z += fmaxf(a.z, 0.f);
            s.w += fmaxf(a.w, 0.f);
        }
        r[i] = s;
        sumsq += s.x * s.x + s.y * s.y + s.z * s.z + s.w * s.w;
    }

    // 64-lane butterfly reduce within each wave
#pragma unroll
    for (int off = 32; off >= 1; off >>= 1)
        sumsq += __shfl_xor(sumsq, off, 64);

    // cross-wave reduce (4 waves per block)
    __shared__ float wsum[4];
    if ((tid & 63) == 0) wsum[tid >> 6] = sumsq;
    __syncthreads();
    const float total = wsum[0] + wsum[1] + wsum[2] + wsum[3];
    const float scale = rsqrtf(total / (float)hidden + kEps);

#pragma unroll
    for (int i = 0; i < ITERS; ++i) {
        const int e = (i * 256 + tid) * 4;
        const float4 wv = *reinterpret_cast<const float4*>(w + e);
        float4 o;
        o.x = r[i].x * scale * wv.x;
        o.y = r[i].y * scale * wv.y;
        o.z = r[i].z * scale * wv.z;
        o.w = r[i].w * scale * wv.w;
        *reinterpret_cast<float4*>(out + row + e) = o;
    }
}

// Generic fallback (any tp / hidden): two-pass over the input row, scalar.
__global__ void relu_ar_rmsnorm_generic(
    const float* __restrict__ x,
    const float* __restrict__ w,
    float* __restrict__ out,
    int tp, int tokens, int hidden)
{
    const int tid = threadIdx.x;
    const long long row = (long long)blockIdx.x * hidden;
    const long long rstride = (long long)tokens * hidden;

    float sumsq = 0.f;
    for (int e = tid; e < hidden; e += blockDim.x) {
        float s = 0.f;
        for (int rk = 0; rk < tp; ++rk)
            s += fmaxf(x[rk * rstride + row + e], 0.f);
        sumsq += s * s;
    }
#pragma unroll
    for (int off = 32; off >= 1; off >>= 1)
        sumsq += __shfl_xor(sumsq, off, 64);

    __shared__ float wsum[16];
    const int nwaves = (blockDim.x + 63) >> 6;
    if ((tid & 63) == 0) wsum[tid >> 6] = sumsq;
    __syncthreads();
    float total = 0.f;
    for (int i = 0; i < nwaves; ++i) total += wsum[i];
    const float scale = rsqrtf(total / (float)hidden + kEps);

    for (int e = tid; e < hidden; e += blockDim.x) {
        float s = 0.f;
        for (int rk = 0; rk < tp; ++rk)
            s += fmaxf(x[rk * rstride + row + e], 0.f);
        out[row + e] = s * scale * w[e];
    }
}

extern "C" void kernel_launch(void* const* d_in, const int* in_sizes, int n_in,
                              void* d_out, int out_size, void* d_ws, size_t ws_size,
                              hipStream_t stream) {
    const float* x = (const float*)d_in[0];
    const float* w = (const float*)d_in[1];
    float* out = (float*)d_out;

    const int hidden = in_sizes[1];            // 4096
    const int tokens = out_size / hidden;      // 8192
    const int tp = in_sizes[0] / out_size;     // 4

    if (tp == 4 && hidden == 4096) {
        relu_ar_rmsnorm_kernel<4, 4><<<dim3(tokens), dim3(256), 0, stream>>>(
            x, w, out, tokens, hidden);
    } else {
        relu_ar_rmsnorm_generic<<<dim3(tokens), dim3(256), 0, stream>>>(
            x, w, out, tp, tokens, hidden);
    }
}

// Round 3
// 123.796 us; speedup vs baseline: 1.0181x; 1.0181x over previous
//
#include <hip/hip_runtime.h>
#include <hip/hip_bf16.h>

static constexpr float kEps = 1e-6f;

typedef float f32x4 __attribute__((ext_vector_type(4)));

// Fused relu -> tp-sum -> RMSNorm, persistent-grid version.
// 2048 resident blocks (256 threads) grid-stride over token rows.
// Per row: 4 float4 loads per rank per thread (fully coalesced), relu+sum in
// registers, 64-lane butterfly + 4-entry LDS cross-wave reduce, nontemporal
// vector stores (output is never re-read -> don't pollute L2).
template <int TP, int ITERS>
__global__ __launch_bounds__(256) void relu_ar_rmsnorm_persistent(
    const float* __restrict__ x,      // [TP, tokens, hidden]
    const float* __restrict__ w,      // [hidden]
    float* __restrict__ out,          // [tokens, hidden]
    int tokens, int hidden)
{
    const int tid = threadIdx.x;
    const long long rstride = (long long)tokens * hidden;

    __shared__ float wsum[4];

    for (int rowi = blockIdx.x; rowi < tokens; rowi += gridDim.x) {
        const long long row = (long long)rowi * hidden;

        f32x4 r[ITERS];
        float sumsq = 0.f;

#pragma unroll
        for (int i = 0; i < ITERS; ++i) {
            const int e = (i * 256 + tid) * 4;
            f32x4 s = (f32x4)(0.f);
#pragma unroll
            for (int rk = 0; rk < TP; ++rk) {
                const f32x4 a = *reinterpret_cast<const f32x4*>(x + rk * rstride + row + e);
                s.x += fmaxf(a.x, 0.f);
                s.y += fmaxf(a.y, 0.f);
                s.z += fmaxf(a.z, 0.f);
                s.w += fmaxf(a.w, 0.f);
            }
            r[i] = s;
            sumsq += s.x * s.x + s.y * s.y + s.z * s.z + s.w * s.w;
        }

        // 64-lane butterfly reduce within each wave
#pragma unroll
        for (int off = 32; off >= 1; off >>= 1)
            sumsq += __shfl_xor(sumsq, off, 64);

        // cross-wave reduce (4 waves per block)
        if ((tid & 63) == 0) wsum[tid >> 6] = sumsq;
        __syncthreads();
        const float total = wsum[0] + wsum[1] + wsum[2] + wsum[3];
        // protect wsum from being overwritten by a fast wave in the next row
        __syncthreads();

        const float scale = rsqrtf(total / (float)hidden + kEps);

#pragma unroll
        for (int i = 0; i < ITERS; ++i) {
            const int e = (i * 256 + tid) * 4;
            const f32x4 wv = *reinterpret_cast<const f32x4*>(w + e);
            f32x4 o;
            o.x = r[i].x * scale * wv.x;
            o.y = r[i].y * scale * wv.y;
            o.z = r[i].z * scale * wv.z;
            o.w = r[i].w * scale * wv.w;
            __builtin_nontemporal_store(o, reinterpret_cast<f32x4*>(out + row + e));
        }
    }
}

// Generic fallback (any tp / hidden): two-pass over the input row, scalar.
__global__ void relu_ar_rmsnorm_generic(
    const float* __restrict__ x,
    const float* __restrict__ w,
    float* __restrict__ out,
    int tp, int tokens, int hidden)
{
    const int tid = threadIdx.x;
    const long long row = (long long)blockIdx.x * hidden;
    const long long rstride = (long long)tokens * hidden;

    float sumsq = 0.f;
    for (int e = tid; e < hidden; e += blockDim.x) {
        float s = 0.f;
        for (int rk = 0; rk < tp; ++rk)
            s += fmaxf(x[rk * rstride + row + e], 0.f);
        sumsq += s * s;
    }
#pragma unroll
    for (int off = 32; off >= 1; off >>= 1)
        sumsq += __shfl_xor(sumsq, off, 64);

    __shared__ float wsum[16];
    const int nwaves = (blockDim.x + 63) >> 6;
    if ((tid & 63) == 0) wsum[tid >> 6] = sumsq;
    __syncthreads();
    float total = 0.f;
    for (int i = 0; i < nwaves; ++i) total += wsum[i];
    const float scale = rsqrtf(total / (float)hidden + kEps);

    for (int e = tid; e < hidden; e += blockDim.x) {
        float s = 0.f;
        for (int rk = 0; rk < tp; ++rk)
            s += fmaxf(x[rk * rstride + row + e], 0.f);
        out[row + e] = s * scale * w[e];
    }
}

extern "C" void kernel_launch(void* const* d_in, const int* in_sizes, int n_in,
                              void* d_out, int out_size, void* d_ws, size_t ws_size,
                              hipStream_t stream) {
    const float* x = (const float*)d_in[0];
    const float* w = (const float*)d_in[1];
    float* out = (float*)d_out;

    const int hidden = in_sizes[1];            // 4096
    const int tokens = out_size / hidden;      // 8192
    const int tp = in_sizes[0] / out_size;     // 4

    if (tp == 4 && hidden == 4096) {
        const int grid = tokens < 2048 ? tokens : 2048;
        relu_ar_rmsnorm_persistent<4, 4><<<dim3(grid), dim3(256), 0, stream>>>(
            x, w, out, tokens, hidden);
    } else {
        relu_ar_rmsnorm_generic<<<dim3(tokens), dim3(256), 0, stream>>>(
            x, w, out, tp, tokens, hidden);
    }
}